// Round 1
// baseline (202.462 us; speedup 1.0000x reference)
//
#include <hip/hip_runtime.h>

#define HW      147456           // 384*384
#define NC      5
#define NT      40               // 4*10 time-batch slices
#define GPS     36864            // float4 groups per slice (HW/4)
#define BX      72               // blocks along x  -> 72*256 = 18432 threads/slice
#define TPS     (BX * 256)       // threads per slice
#define NBLK    (BX * NT)        // 2880 blocks total
#define SMOOTH  1e-5f

// Per-block partial sums are written to ws[j*NBLK + blockFlat], j in [0,15):
//   j = 0..4  : sum(x) per class
//   j = 5..9  : sum(x * onehot) per class
//   j = 10..14: count(onehot) per class
// Plain stores -> no workspace init kernel, no atomic contention.

__global__ __launch_bounds__(256) void dice_main(const float* __restrict__ inp,
                                                 const float* __restrict__ tgt,
                                                 float* __restrict__ ws) {
    const int nt = blockIdx.y;                       // scalar per block
    const int t0 = blockIdx.x * 256 + threadIdx.x;   // 0..18431 within slice

    // Scalar (SGPR) tile bases: nt is wave-uniform.
    const float* __restrict__ tb = tgt + (size_t)nt * (size_t)HW;
    const float* __restrict__ ib = inp + (size_t)nt * (size_t)(NC * HW);

    float sumx[NC]  = {0.f, 0.f, 0.f, 0.f, 0.f};
    float inter[NC] = {0.f, 0.f, 0.f, 0.f, 0.f};
    float cnt[NC]   = {0.f, 0.f, 0.f, 0.f, 0.f};

    #pragma unroll
    for (int it = 0; it < 2; ++it) {
        const int g = t0 + it * TPS;                 // group index within slice, < 36864
        const float4 t4 = reinterpret_cast<const float4*>(tb)[g];

        const int c0 = (t4.x >= 0.25f) + (t4.x >= 0.375f) + (t4.x >= 0.5f) + (t4.x >= 0.625f);
        const int c1 = (t4.y >= 0.25f) + (t4.y >= 0.375f) + (t4.y >= 0.5f) + (t4.y >= 0.625f);
        const int c2 = (t4.z >= 0.25f) + (t4.z >= 0.375f) + (t4.z >= 0.5f) + (t4.z >= 0.625f);
        const int c3 = (t4.w >= 0.25f) + (t4.w >= 0.375f) + (t4.w >= 0.5f) + (t4.w >= 0.625f);

        const float* base = ib + ((size_t)g << 2);
        #pragma unroll
        for (int c = 0; c < NC; ++c) {
            const float4 x4 = *reinterpret_cast<const float4*>(base + (size_t)c * HW);
            sumx[c] += (x4.x + x4.y) + (x4.z + x4.w);
            float iv = 0.f;
            if (c0 == c) iv += x4.x;
            if (c1 == c) iv += x4.y;
            if (c2 == c) iv += x4.z;
            if (c3 == c) iv += x4.w;
            inter[c] += iv;
            cnt[c]   += (float)((c0 == c) + (c1 == c) + (c2 == c) + (c3 == c));
        }
    }

    // pack 15 accumulators
    float v[15];
    #pragma unroll
    for (int c = 0; c < NC; ++c) { v[c] = sumx[c]; v[5 + c] = inter[c]; v[10 + c] = cnt[c]; }

    // wave-64 butterfly reduce
    #pragma unroll
    for (int j = 0; j < 15; ++j) {
        #pragma unroll
        for (int off = 32; off > 0; off >>= 1)
            v[j] += __shfl_down(v[j], off, 64);
    }

    __shared__ float part[4][15];
    const int lane = threadIdx.x & 63;
    const int wv   = threadIdx.x >> 6;
    if (lane == 0) {
        #pragma unroll
        for (int j = 0; j < 15; ++j) part[wv][j] = v[j];
    }
    __syncthreads();
    if (threadIdx.x < 15) {
        const float s = part[0][threadIdx.x] + part[1][threadIdx.x] +
                        part[2][threadIdx.x] + part[3][threadIdx.x];
        // transposed layout: ws[j*NBLK + b] so the final kernel reads coalesced
        ws[threadIdx.x * NBLK + (blockIdx.y * BX + blockIdx.x)] = s;
    }
}

__global__ __launch_bounds__(960) void dice_final(const float* __restrict__ ws,
                                                  const float* __restrict__ w,
                                                  float* __restrict__ out) {
    __shared__ float red[15];
    const int j    = threadIdx.x >> 6;   // 15 waves, one per accumulator slot
    const int lane = threadIdx.x & 63;

    float s = 0.f;
    for (int b = lane; b < NBLK; b += 64)   // 45 coalesced iterations
        s += ws[j * NBLK + b];

    #pragma unroll
    for (int off = 32; off > 0; off >>= 1)
        s += __shfl_down(s, off, 64);

    if (lane == 0) red[j] = s;
    __syncthreads();

    if (threadIdx.x == 0) {
        float loss = 0.f;
        #pragma unroll
        for (int c = 0; c < NC; ++c) {
            const float inter = red[5 + c];
            const float denom = red[c] + red[10 + c];
            loss += w[c] * (1.f - (2.f * inter + SMOOTH) / (denom + SMOOTH));
        }
        out[0] = loss;
    }
}

extern "C" void kernel_launch(void* const* d_in, const int* in_sizes, int n_in,
                              void* d_out, int out_size, void* d_ws, size_t ws_size,
                              hipStream_t stream) {
    const float* inp = (const float*)d_in[0];
    const float* tgt = (const float*)d_in[1];
    const float* wgt = (const float*)d_in[2];
    float* out = (float*)d_out;
    float* ws  = (float*)d_ws;

    // (72,40) grid: nt is uniform per block (scalar bases), exactly 2 float4-groups
    // per thread, 11.25 blocks/CU for even residency. No init kernel needed.
    dice_main<<<dim3(BX, NT), 256, 0, stream>>>(inp, tgt, ws);
    dice_final<<<1, 960, 0, stream>>>(ws, wgt, out);
}